// Round 1
// baseline (999.435 us; speedup 1.0000x reference)
//
#include <hip/hip_runtime.h>
#include <hip/hip_bf16.h>

// vector types matching MFMA register counts
typedef __bf16 bf16x8 __attribute__((ext_vector_type(8)));   // 4 VGPRs (A/B frag)
typedef float  f32x4  __attribute__((ext_vector_type(4)));   // 4 VGPRs (C/D frag)

// async global->LDS, 16B per lane. LDS dest = wave-uniform base + lane*16.
__device__ __forceinline__ void async_copy16(const void* gsrc, void* ldst) {
  __builtin_amdgcn_global_load_lds(
      (__attribute__((address_space(1))) void*)(gsrc),
      (__attribute__((address_space(3))) void*)(ldst),
      16, 0, 0);
}

// Bijective XCD chunking (m204). HW round-robins consecutive blockIdx across
// the 8 XCDs (XCD = orig % 8); remap so each XCD owns a CONTIGUOUS wgid chunk
// -> the 16-block cohorts sharing an A-tile stay inside one XCD's L2.
__device__ __forceinline__ int xcd_swizzle(int orig, int nwg) {
  const int q = nwg >> 3, r = nwg & 7;
  const int xcd = orig & 7, lin = orig >> 3;
  return (xcd < r ? xcd * (q + 1) : r * (q + 1) + (xcd - r) * q) + lin;
}

// ---------------------------------------------------------------------------
// Cast all five fp32 tensors to bf16 scratch in one launch.
// Chunk = 8 elements. Region boundaries (in chunks):
//   enc_out 51200 | pred_out 25600 | enc_w 32768 | pred_w 32768 | out_w 131072
// cum: 51200, 76800, 109568, 142336, 273408  (= 1068 * 256 exactly)
// ---------------------------------------------------------------------------
__global__ __launch_bounds__(256) void cast_all(
    const float* __restrict__ s0, const float* __restrict__ s1,
    const float* __restrict__ s2, const float* __restrict__ s3,
    const float* __restrict__ s4,
    __bf16* __restrict__ d0, __bf16* __restrict__ d1, __bf16* __restrict__ d2,
    __bf16* __restrict__ d3, __bf16* __restrict__ d4) {
  const int c = blockIdx.x * 256 + threadIdx.x;
  const float* s; __bf16* d; int off;
  if (c < 51200)       { s = s0; d = d0; off = c; }
  else if (c < 76800)  { s = s1; d = d1; off = c - 51200; }
  else if (c < 109568) { s = s2; d = d2; off = c - 76800; }
  else if (c < 142336) { s = s3; d = d3; off = c - 109568; }
  else                 { s = s4; d = d4; off = c - 142336; }
  const float4* sp = (const float4*)(s + (size_t)off * 8);
  const float4 a = sp[0], b = sp[1];
  bf16x8 o;
  o[0] = (__bf16)a.x; o[1] = (__bf16)a.y; o[2] = (__bf16)a.z; o[3] = (__bf16)a.w;
  o[4] = (__bf16)b.x; o[5] = (__bf16)b.y; o[6] = (__bf16)b.z; o[7] = (__bf16)b.w;
  *(bf16x8*)(d + (size_t)off * 8) = o;
}

// ---------------------------------------------------------------------------
// NT GEMM body: C[m,n] = sum_k A[m,k]*B[n,k] + bias[n]  (A,B bf16; bias,C fp32)
// A: [M,K] row-major, B: [N,K] row-major, K mult of 64, N mult of 128,
// M arbitrary (loads clamped, stores guarded).
// 128x128 tile, BK=64, 256 threads = 4 waves (2x2), wave = 4x4 grid of
// v_mfma_f32_16x16x32_bf16.
// LDS: 1024 16B chunks; chunk q holds global (row=q>>3, kc=(q&7)^(row&7)).
// XOR swizzle on the GLOBAL side (global_load_lds needs lane-contiguous LDS);
// keeps global reads in one 128B row segment, frag ds_read_b128 <=2-way
// conflicted (free, m136).
// ---------------------------------------------------------------------------
__device__ __forceinline__ void gemm_body(
    const __bf16* __restrict__ A, const __bf16* __restrict__ B,
    const float* __restrict__ bias, float* __restrict__ C,
    const int M, const int N, const int K, const int bn, const int bm,
    __bf16* sA, __bf16* sB) {
  const int tid  = threadIdx.x;
  const int wave = tid >> 6;
  const int lane = tid & 63;
  const int quad = lane >> 4;
  const int l16  = lane & 15;

  f32x4 acc[4][4];
#pragma unroll
  for (int i = 0; i < 4; ++i)
#pragma unroll
    for (int j = 0; j < 4; ++j) {
      acc[i][j][0] = 0.f; acc[i][j][1] = 0.f;
      acc[i][j][2] = 0.f; acc[i][j][3] = 0.f;
    }

  const int wm = (wave >> 1) * 64;
  const int wn = (wave & 1) * 64;

  const int nK = K >> 6;
  for (int kt = 0; kt < nK; ++kt) {
    const int k0 = kt << 6;
#pragma unroll
    for (int i = 0; i < 4; ++i) {
      const int f   = i * 256 + tid;        // chunk this lane fetches
      const int row = f >> 3;
      const int kc  = (f & 7) ^ (row & 7);  // XOR swizzle (global side)
      int ar = bm * 128 + row; if (ar >= M) ar = M - 1;  // clamp: no fault
      const __bf16* gA = A + (size_t)ar * K + k0 + kc * 8;
      async_copy16((const void*)gA, (void*)(sA + (i * 256 + wave * 64) * 8));
      const int br = bn * 128 + row;        // N mult of 128: in bounds
      const __bf16* gB = B + (size_t)br * K + k0 + kc * 8;
      async_copy16((const void*)gB, (void*)(sB + (i * 256 + wave * 64) * 8));
    }
    __syncthreads();  // compiler emits s_waitcnt vmcnt(0) before s_barrier

#pragma unroll
    for (int ks = 0; ks < 2; ++ks) {
      bf16x8 af[4], bfr[4];
#pragma unroll
      for (int mi = 0; mi < 4; ++mi) {
        const int row = wm + mi * 16 + l16;
        const int cc  = (ks * 4 + quad) ^ (row & 7);
        af[mi] = *(const bf16x8*)(sA + (row * 8 + cc) * 8);
      }
#pragma unroll
      for (int ni = 0; ni < 4; ++ni) {
        const int row = wn + ni * 16 + l16;
        const int cc  = (ks * 4 + quad) ^ (row & 7);
        bfr[ni] = *(const bf16x8*)(sB + (row * 8 + cc) * 8);
      }
#pragma unroll
      for (int mi = 0; mi < 4; ++mi)
#pragma unroll
        for (int ni = 0; ni < 4; ++ni)
          acc[mi][ni] = __builtin_amdgcn_mfma_f32_16x16x32_bf16(
              af[mi], bfr[ni], acc[mi][ni], 0, 0, 0);
    }
    __syncthreads();
  }

  // epilogue: C/D layout n = lane&15, m = quad*4 + reg  (m89-verified)
#pragma unroll
  for (int ni = 0; ni < 4; ++ni) {
    const int n = bn * 128 + wn + ni * 16 + l16;
    const float bs = bias[n];
#pragma unroll
    for (int mi = 0; mi < 4; ++mi) {
      const int mbase = bm * 128 + wm + mi * 16 + quad * 4;
#pragma unroll
      for (int r = 0; r < 4; ++r) {
        const int m = mbase + r;
        if (m < M) C[(size_t)m * N + n] = acc[mi][ni][r] + bs;
      }
    }
  }
}

// Main GEMM wrapper: XCD-aware swizzle + 3-blocks/CU VGPR cap.
// acc(64) + frags(32) + addressing ~= 130 VGPR -> fits the 168-VGPR/3-wave
// budget (m97's structure compiled to 164); LDS 32KB allows 5 blocks/CU.
__global__ __launch_bounds__(256, 3) void gemm_bias_nt(
    const __bf16* __restrict__ A, const __bf16* __restrict__ B,
    const float* __restrict__ bias, float* __restrict__ C,
    int M, int N, int K) {
  __shared__ __bf16 sA[128 * 64];
  __shared__ __bf16 sB[128 * 64];
  const int nwg  = (int)(gridDim.x * gridDim.y);
  const int wgid = xcd_swizzle((int)(blockIdx.y * gridDim.x + blockIdx.x), nwg);
  const int bn = wgid % (int)gridDim.x;
  const int bm = wgid / (int)gridDim.x;
  gemm_body(A, B, bias, C, M, N, K, bn, bm, sA, sB);
}

// Dual-region wrapper: runs the enc (bm < split) and pred (bm >= split)
// projections in ONE launch -> overlaps two latency-bound small GEMMs.
// Tiny grid (44 blocks): no XCD swizzle (spread is good for utilization).
__global__ __launch_bounds__(256, 2) void gemm_bias_nt_dual(
    const __bf16* __restrict__ A0, const __bf16* __restrict__ B0,
    const float* __restrict__ bias0, float* __restrict__ C0, int M0, int split,
    const __bf16* __restrict__ A1, const __bf16* __restrict__ B1,
    const float* __restrict__ bias1, float* __restrict__ C1, int M1,
    int N, int K) {
  __shared__ __bf16 sA[128 * 64];
  __shared__ __bf16 sB[128 * 64];
  const int wgid = (int)(blockIdx.y * gridDim.x + blockIdx.x);
  int bn = wgid % (int)gridDim.x;
  int bm = wgid / (int)gridDim.x;
  const __bf16* A = A0; const __bf16* B = B0;
  const float* bias = bias0; float* C = C0; int M = M0;
  if (bm >= split) { A = A1; B = B1; bias = bias1; C = C1; M = M1; bm -= split; }
  gemm_body(A, B, bias, C, M, N, K, bn, bm, sA, sB);
}

// ---------------------------------------------------------------------------
// joint: h[row,:] = bf16(tanh(e[row/100,:] + p[(row/20000)*100 + row%100,:]))
// 8 elems/thread. e/p tiny (2.4MB) -> L2-hot. tanh(x)=1-2/(exp2(2x*log2e)+1);
// endpoints exact (+-1).
// ---------------------------------------------------------------------------
__global__ __launch_bounds__(256) void joint_tanh(
    const float* __restrict__ e, const float* __restrict__ p,
    __bf16* __restrict__ h) {
  const int chunk = blockIdx.x * 256 + threadIdx.x;  // [0, 80000*64)
  const int row = chunk >> 6;          // (b*200+t)*100 + u
  const int kc  = chunk & 63;
  const int er  = row / 100;           // b*200 + t
  const int b   = row / 20000;
  const int u   = row - er * 100;
  const int pr  = b * 100 + u;

  const float4* ep = (const float4*)(e + (size_t)er * 512 + kc * 8);
  const float4* pp = (const float4*)(p + (size_t)pr * 512 + kc * 8);
  const float4 e0 = ep[0], e1 = ep[1];
  const float4 p0 = pp[0], p1 = pp[1];

  const float x[8] = {e0.x + p0.x, e0.y + p0.y, e0.z + p0.z, e0.w + p0.w,
                      e1.x + p1.x, e1.y + p1.y, e1.z + p1.z, e1.w + p1.w};
  bf16x8 o;
#pragma unroll
  for (int i = 0; i < 8; ++i) {
    const float t  = __builtin_amdgcn_exp2f(x[i] * 2.8853900817779268f);
    const float th = 1.f - 2.f * __builtin_amdgcn_rcpf(t + 1.f);
    o[i] = (__bf16)th;
  }
  *(bf16x8*)(h + (size_t)chunk * 8) = o;
}

// ---------------------------------------------------------------------------
extern "C" void kernel_launch(void* const* d_in, const int* in_sizes, int n_in,
                              void* d_out, int out_size, void* d_ws,
                              size_t ws_size, hipStream_t stream) {
  const float* enc_out  = (const float*)d_in[0];  // [4,200,512] fp32
  const float* pred_out = (const float*)d_in[1];  // [4,100,512]
  const float* enc_w    = (const float*)d_in[2];  // [512,512]
  const float* enc_b    = (const float*)d_in[3];  // [512]
  const float* pred_w   = (const float*)d_in[4];  // [512,512]
  const float* pred_b   = (const float*)d_in[5];  // [512]
  const float* out_w    = (const float*)d_in[6];  // [2048,512]
  const float* out_b    = (const float*)d_in[7];  // [2048]
  float* out = (float*)d_out;                     // [4,200,100,2048] fp32

  char* ws = (char*)d_ws;   // total use: ~88.8 MB
  __bf16* h       = (__bf16*)ws;                    // 80000*512*2 = 81,920,000
  float*  e       = (float*)(ws + 81920000);        // 800*512*4   =  1,638,400
  float*  p       = (float*)(ws + 83558400);        // 400*512*4   =    819,200
  __bf16* enc16   = (__bf16*)(ws + 84377600);       // 409600*2    =    819,200
  __bf16* pred16  = (__bf16*)(ws + 85196800);       // 204800*2    =    409,600
  __bf16* encw16  = (__bf16*)(ws + 85606400);       // 262144*2    =    524,288
  __bf16* predw16 = (__bf16*)(ws + 86130688);       // 262144*2    =    524,288
  __bf16* outw16  = (__bf16*)(ws + 86654976);       // 1048576*2   =  2,097,152

  const dim3 blk(256);
  // 0) cast fp32 inputs -> bf16 scratch
  hipLaunchKernelGGL(cast_all, dim3(1068), blk, 0, stream,
                     enc_out, pred_out, enc_w, pred_w, out_w,
                     enc16, pred16, encw16, predw16, outw16);
  // 1+2) e = enc_out @ enc_w^T + enc_b (M=800) and
  //      p = pred_out @ pred_w^T + pred_b (M=400) in ONE launch.
  //      grid (4, 7+4): bm<7 -> e rows, bm>=7 -> p rows.
  hipLaunchKernelGGL(gemm_bias_nt_dual, dim3(4, 11), blk, 0, stream,
                     enc16, encw16, enc_b, e, 800, 7,
                     pred16, predw16, pred_b, p, 400, 512, 512);
  // 3) h = bf16(tanh(e + p)), [80000, 512]
  hipLaunchKernelGGL(joint_tanh, dim3(20000), blk, 0, stream, e, p, h);
  // 4) out = h @ out_w^T + out_b  (M=80000, N=2048, K=512)
  hipLaunchKernelGGL(gemm_bias_nt, dim3(16, 625), blk, 0, stream,
                     h, outw16, out_b, out, 80000, 2048, 512);
}

// Round 2
// 783.297 us; speedup vs baseline: 1.2759x; 1.2759x over previous
//
#include <hip/hip_runtime.h>
#include <hip/hip_bf16.h>

// vector types matching MFMA register counts
typedef __bf16 bf16x8 __attribute__((ext_vector_type(8)));   // 4 VGPRs (A/B frag)
typedef float  f32x4  __attribute__((ext_vector_type(4)));   // 4 VGPRs (C/D frag)

// async global->LDS, 16B per lane. LDS dest = wave-uniform base + lane*16.
__device__ __forceinline__ void async_copy16(const void* gsrc, void* ldst) {
  __builtin_amdgcn_global_load_lds(
      (__attribute__((address_space(1))) void*)(gsrc),
      (__attribute__((address_space(3))) void*)(ldst),
      16, 0, 0);
}

// Bijective XCD chunking (m204): each XCD owns a contiguous wgid chunk.
__device__ __forceinline__ int xcd_swizzle(int orig, int nwg) {
  const int q = nwg >> 3, r = nwg & 7;
  const int xcd = orig & 7, lin = orig >> 3;
  return (xcd < r ? xcd * (q + 1) : r * (q + 1) + (xcd - r) * q) + lin;
}

// ---------------------------------------------------------------------------
// Cast all five fp32 tensors to bf16 scratch in one launch.
// Chunk = 8 elements. Region boundaries (in chunks):
//   enc_out 51200 | pred_out 25600 | enc_w 32768 | pred_w 32768 | out_w 131072
// cum: 51200, 76800, 109568, 142336, 273408  (= 1068 * 256 exactly)
// ---------------------------------------------------------------------------
__global__ __launch_bounds__(256) void cast_all(
    const float* __restrict__ s0, const float* __restrict__ s1,
    const float* __restrict__ s2, const float* __restrict__ s3,
    const float* __restrict__ s4,
    __bf16* __restrict__ d0, __bf16* __restrict__ d1, __bf16* __restrict__ d2,
    __bf16* __restrict__ d3, __bf16* __restrict__ d4) {
  const int c = blockIdx.x * 256 + threadIdx.x;
  const float* s; __bf16* d; int off;
  if (c < 51200)       { s = s0; d = d0; off = c; }
  else if (c < 76800)  { s = s1; d = d1; off = c - 51200; }
  else if (c < 109568) { s = s2; d = d2; off = c - 76800; }
  else if (c < 142336) { s = s3; d = d3; off = c - 109568; }
  else                 { s = s4; d = d4; off = c - 142336; }
  const float4* sp = (const float4*)(s + (size_t)off * 8);
  const float4 a = sp[0], b = sp[1];
  bf16x8 o;
  o[0] = (__bf16)a.x; o[1] = (__bf16)a.y; o[2] = (__bf16)a.z; o[3] = (__bf16)a.w;
  o[4] = (__bf16)b.x; o[5] = (__bf16)b.y; o[6] = (__bf16)b.z; o[7] = (__bf16)b.w;
  *(bf16x8*)(d + (size_t)off * 8) = o;
}

// ---------------------------------------------------------------------------
// Generic NT GEMM body (used only for the small e/p projections).
// 128x128 tile, BK=64, 256 threads = 4 waves (2x2), wave = 4x4 grid of
// v_mfma_f32_16x16x32_bf16. XOR swizzle on the GLOBAL side.
// ---------------------------------------------------------------------------
__device__ __forceinline__ void gemm_body(
    const __bf16* __restrict__ A, const __bf16* __restrict__ B,
    const float* __restrict__ bias, float* __restrict__ C,
    const int M, const int N, const int K, const int bn, const int bm,
    __bf16* sA, __bf16* sB) {
  const int tid  = threadIdx.x;
  const int wave = tid >> 6;
  const int lane = tid & 63;
  const int quad = lane >> 4;
  const int l16  = lane & 15;

  f32x4 acc[4][4];
#pragma unroll
  for (int i = 0; i < 4; ++i)
#pragma unroll
    for (int j = 0; j < 4; ++j) {
      acc[i][j][0] = 0.f; acc[i][j][1] = 0.f;
      acc[i][j][2] = 0.f; acc[i][j][3] = 0.f;
    }

  const int wm = (wave >> 1) * 64;
  const int wn = (wave & 1) * 64;

  const int nK = K >> 6;
  for (int kt = 0; kt < nK; ++kt) {
    const int k0 = kt << 6;
#pragma unroll
    for (int i = 0; i < 4; ++i) {
      const int f   = i * 256 + tid;
      const int row = f >> 3;
      const int kc  = (f & 7) ^ (row & 7);
      int ar = bm * 128 + row; if (ar >= M) ar = M - 1;  // clamp: no fault
      const __bf16* gA = A + (size_t)ar * K + k0 + kc * 8;
      async_copy16((const void*)gA, (void*)(sA + (i * 256 + wave * 64) * 8));
      const int br = bn * 128 + row;
      const __bf16* gB = B + (size_t)br * K + k0 + kc * 8;
      async_copy16((const void*)gB, (void*)(sB + (i * 256 + wave * 64) * 8));
    }
    __syncthreads();

#pragma unroll
    for (int ks = 0; ks < 2; ++ks) {
      bf16x8 af[4], bfr[4];
#pragma unroll
      for (int mi = 0; mi < 4; ++mi) {
        const int row = wm + mi * 16 + l16;
        const int cc  = (ks * 4 + quad) ^ (row & 7);
        af[mi] = *(const bf16x8*)(sA + (row * 8 + cc) * 8);
      }
#pragma unroll
      for (int ni = 0; ni < 4; ++ni) {
        const int row = wn + ni * 16 + l16;
        const int cc  = (ks * 4 + quad) ^ (row & 7);
        bfr[ni] = *(const bf16x8*)(sB + (row * 8 + cc) * 8);
      }
#pragma unroll
      for (int mi = 0; mi < 4; ++mi)
#pragma unroll
        for (int ni = 0; ni < 4; ++ni)
          acc[mi][ni] = __builtin_amdgcn_mfma_f32_16x16x32_bf16(
              af[mi], bfr[ni], acc[mi][ni], 0, 0, 0);
    }
    __syncthreads();
  }

  // epilogue: C/D layout n = lane&15, m = quad*4 + reg  (m89-verified)
#pragma unroll
  for (int ni = 0; ni < 4; ++ni) {
    const int n = bn * 128 + wn + ni * 16 + l16;
    const float bs = bias[n];
#pragma unroll
    for (int mi = 0; mi < 4; ++mi) {
      const int mbase = bm * 128 + wm + mi * 16 + quad * 4;
#pragma unroll
      for (int r = 0; r < 4; ++r) {
        const int m = mbase + r;
        if (m < M) C[(size_t)m * N + n] = acc[mi][ni][r] + bs;
      }
    }
  }
}

// Dual-region wrapper: enc (bm < split) and pred (bm >= split) projections
// in ONE launch (overlaps two latency-bound small GEMMs).
__global__ __launch_bounds__(256, 2) void gemm_bias_nt_dual(
    const __bf16* __restrict__ A0, const __bf16* __restrict__ B0,
    const float* __restrict__ bias0, float* __restrict__ C0, int M0, int split,
    const __bf16* __restrict__ A1, const __bf16* __restrict__ B1,
    const float* __restrict__ bias1, float* __restrict__ C1, int M1,
    int N, int K) {
  __shared__ __bf16 sA[128 * 64];
  __shared__ __bf16 sB[128 * 64];
  const int wgid = (int)(blockIdx.y * gridDim.x + blockIdx.x);
  int bn = wgid % (int)gridDim.x;
  int bm = wgid / (int)gridDim.x;
  const __bf16* A = A0; const __bf16* B = B0;
  const float* bias = bias0; float* C = C0; int M = M0;
  if (bm >= split) { A = A1; B = B1; bias = bias1; C = C1; M = M1; bm -= split; }
  gemm_body(A, B, bias, C, M, N, K, bn, bm, sA, sB);
}

// ---------------------------------------------------------------------------
// FUSED joint GEMM: out[m, n] = sum_k tanh(e[er(m),k] + p[pr(m),k]) * W[n,k]
//                              + bias[n]
// M=80000 (= 625*128 exactly, no guard), N=2048 (= 8*256), K=512.
// BM=128, BN=256, BK=64. 512 threads = 8 waves (2M x 4N), each wave the
// proven 64x64 acc[4][4] 16x16x32 shape.
// A-tile is COMPUTED in-register from e/p (both L2-resident, ~2.4 MB total)
// and ds_write'n with the same XOR swizzle the ds_read side expects:
//   LDS chunk q (16B) holds (row = q>>3, kchunk = (q&7)^(row&7)).
// B staged via global_load_lds (out_w bf16, 2 MB, L2-resident).
// h never touches HBM: kills the 212 MB refetch + 82 MB write + the
// 900-cycle HBM-latency vmcnt drains that made the old GEMM4 latency-bound.
// C written nontemporal: keeps the 655 MB stream from evicting e/p/W in L2.
// ---------------------------------------------------------------------------
__global__ __launch_bounds__(512, 4) void joint_gemm(
    const float* __restrict__ e, const float* __restrict__ p,
    const __bf16* __restrict__ W, const float* __restrict__ bias,
    float* __restrict__ C) {
  const int tid  = threadIdx.x;
  const int wave = tid >> 6;
  const int lane = tid & 63;
  const int quad = lane >> 4;
  const int l16  = lane & 15;

  __shared__ __bf16 sA[128 * 64];   // 16 KB
  __shared__ __bf16 sB[256 * 64];   // 32 KB  -> 48 KB total, 2 blocks/CU OK

  const int wgid = xcd_swizzle((int)(blockIdx.y * gridDim.x + blockIdx.x),
                               (int)(gridDim.x * gridDim.y));
  const int bn = wgid & 7;          // gridDim.x == 8
  const int bm = wgid >> 3;         // 0..624

  // Per-thread A-chunk metadata (2 chunks of 8 elems), hoisted out of K-loop.
  int eoff[2], poff[2], aldsoff[2];
#pragma unroll
  for (int i = 0; i < 2; ++i) {
    const int q   = i * 512 + tid;          // 0..1023
    const int row = q >> 3;                 // 0..127
    const int kc  = (q & 7) ^ (row & 7);    // XOR swizzle (write side)
    const int gr  = bm * 128 + row;         // global h-row, < 80000
    const int er  = gr / 100;               // b*200 + t
    const int b   = gr / 20000;
    const int u   = gr - er * 100;
    const int pr  = b * 100 + u;
    eoff[i] = er * 512 + kc * 8;
    poff[i] = pr * 512 + kc * 8;
    aldsoff[i] = q * 8;                     // element offset into sA
  }
  // Per-thread B-chunk source offsets (4 chunks).
  int boff[4];
#pragma unroll
  for (int i = 0; i < 4; ++i) {
    const int q   = i * 512 + tid;          // 0..2047
    const int row = q >> 3;                 // 0..255
    const int kc  = (q & 7) ^ (row & 7);
    boff[i] = (bn * 256 + row) * 512 + kc * 8;
  }

  f32x4 acc[4][4];
#pragma unroll
  for (int i = 0; i < 4; ++i)
#pragma unroll
    for (int j = 0; j < 4; ++j) {
      acc[i][j][0] = 0.f; acc[i][j][1] = 0.f;
      acc[i][j][2] = 0.f; acc[i][j][3] = 0.f;
    }

  const int wm = (wave >> 2) * 64;   // {0, 64}
  const int wn = (wave & 3) * 64;    // {0, 64, 128, 192}

  for (int kt = 0; kt < 8; ++kt) {
    const int k0 = kt * 64;
    // B first: async-load latency hides under the A tanh VALU work.
#pragma unroll
    for (int i = 0; i < 4; ++i)
      async_copy16((const void*)(W + boff[i] + k0),
                   (void*)(sB + (i * 512 + wave * 64) * 8));
    // A: compute bf16(tanh(e+p)) in-register, swizzled ds_write_b128.
    // tanh(x) = 1 - 2/(exp2(2x*log2e)+1); endpoints exact (+-1).
#pragma unroll
    for (int i = 0; i < 2; ++i) {
      const float4* ep = (const float4*)(e + eoff[i] + k0);
      const float4* pp = (const float4*)(p + poff[i] + k0);
      const float4 e0 = ep[0], e1 = ep[1];
      const float4 p0 = pp[0], p1 = pp[1];
      const float x[8] = {e0.x + p0.x, e0.y + p0.y, e0.z + p0.z, e0.w + p0.w,
                          e1.x + p1.x, e1.y + p1.y, e1.z + p1.z, e1.w + p1.w};
      bf16x8 o;
#pragma unroll
      for (int j = 0; j < 8; ++j) {
        const float t = __builtin_amdgcn_exp2f(x[j] * 2.8853900817779268f);
        o[j] = (__bf16)(1.f - 2.f * __builtin_amdgcn_rcpf(t + 1.f));
      }
      *(bf16x8*)(sA + aldsoff[i]) = o;
    }
    __syncthreads();  // drains vmcnt(0) (B) + lgkmcnt(0) (A writes)

#pragma unroll
    for (int ks = 0; ks < 2; ++ks) {
      bf16x8 af[4], bfr[4];
#pragma unroll
      for (int mi = 0; mi < 4; ++mi) {
        const int row = wm + mi * 16 + l16;
        const int cc  = (ks * 4 + quad) ^ (row & 7);
        af[mi] = *(const bf16x8*)(sA + (row * 8 + cc) * 8);
      }
#pragma unroll
      for (int ni = 0; ni < 4; ++ni) {
        const int row = wn + ni * 16 + l16;
        const int cc  = (ks * 4 + quad) ^ (row & 7);
        bfr[ni] = *(const bf16x8*)(sB + (row * 8 + cc) * 8);
      }
#pragma unroll
      for (int mi = 0; mi < 4; ++mi)
#pragma unroll
        for (int ni = 0; ni < 4; ++ni)
          acc[mi][ni] = __builtin_amdgcn_mfma_f32_16x16x32_bf16(
              af[mi], bfr[ni], acc[mi][ni], 0, 0, 0);
    }
    __syncthreads();
  }

  // epilogue: C/D layout n = lane&15, m = quad*4 + reg; M exact -> no guard.
  // nontemporal: C stream bypasses L2 (protects e/p/W residency).
#pragma unroll
  for (int ni = 0; ni < 4; ++ni) {
    const int n = bn * 256 + wn + ni * 16 + l16;
    const float bs = bias[n];
#pragma unroll
    for (int mi = 0; mi < 4; ++mi) {
      const size_t mb =
          (size_t)(bm * 128 + wm + mi * 16 + quad * 4) * 2048 + n;
#pragma unroll
      for (int r = 0; r < 4; ++r)
        __builtin_nontemporal_store(acc[mi][ni][r] + bs,
                                    C + mb + (size_t)r * 2048);
    }
  }
}

// ---------------------------------------------------------------------------
extern "C" void kernel_launch(void* const* d_in, const int* in_sizes, int n_in,
                              void* d_out, int out_size, void* d_ws,
                              size_t ws_size, hipStream_t stream) {
  const float* enc_out  = (const float*)d_in[0];  // [4,200,512] fp32
  const float* pred_out = (const float*)d_in[1];  // [4,100,512]
  const float* enc_w    = (const float*)d_in[2];  // [512,512]
  const float* enc_b    = (const float*)d_in[3];  // [512]
  const float* pred_w   = (const float*)d_in[4];  // [512,512]
  const float* pred_b   = (const float*)d_in[5];  // [512]
  const float* out_w    = (const float*)d_in[6];  // [2048,512]
  const float* out_b    = (const float*)d_in[7];  // [2048]
  float* out = (float*)d_out;                     // [4,200,100,2048] fp32

  char* ws = (char*)d_ws;   // total use: ~6.8 MB (h eliminated)
  float*  e       = (float*)ws;                     // 800*512*4  = 1,638,400
  float*  p       = (float*)(ws + 1638400);         // 400*512*4  =   819,200
  __bf16* enc16   = (__bf16*)(ws + 2457600);        // 409600*2   =   819,200
  __bf16* pred16  = (__bf16*)(ws + 3276800);        // 204800*2   =   409,600
  __bf16* encw16  = (__bf16*)(ws + 3686400);        // 262144*2   =   524,288
  __bf16* predw16 = (__bf16*)(ws + 4210688);        // 262144*2   =   524,288
  __bf16* outw16  = (__bf16*)(ws + 4734976);        // 1048576*2  = 2,097,152

  const dim3 blk(256);
  // 0) cast fp32 inputs -> bf16 scratch
  hipLaunchKernelGGL(cast_all, dim3(1068), blk, 0, stream,
                     enc_out, pred_out, enc_w, pred_w, out_w,
                     enc16, pred16, encw16, predw16, outw16);
  // 1+2) e = enc_out @ enc_w^T + enc_b (M=800) and
  //      p = pred_out @ pred_w^T + pred_b (M=400) in ONE launch.
  hipLaunchKernelGGL(gemm_bias_nt_dual, dim3(4, 11), blk, 0, stream,
                     enc16, encw16, enc_b, e, 800, 7,
                     pred16, predw16, pred_b, p, 400, 512, 512);
  // 3) out = tanh(e[+]p) @ out_w^T + out_b, fused (M=80000, N=2048, K=512)
  hipLaunchKernelGGL(joint_gemm, dim3(8, 625), dim3(512), 0, stream,
                     e, p, outw16, out_b, out);
}